// Round 5
// baseline (6847.918 us; speedup 1.0000x reference)
//
#include <hip/hip_runtime.h>
#include <math.h>

#define N 4096
#define DIM 64
#define MAX_ITER 50
#define EPS 0.1f
#define INV_EPS 10.0f
#define THRESH 0.1f
#define NBLK 256
#define NTHR 1024
#define QSCALE 128.0f
#define IQSCALE 0.0078125f

// ws layout (bytes):
//   [0,16K): u[4096] | [16K,32K): v[4096]
//   [32K,+): err[64], cost, done_cnt, bar_cnt, bar_gen  (floats from 2N)
//   [64K, 64K+256K): u-partials float2 up[8][4096]
//   [1M, 1M+32M): C16 panels; panel k at 1M + k*4MiB, row-major 4096x512 u16
__global__ void init_ws(float* __restrict__ ws) {
    int i = blockIdx.x * 256 + threadIdx.x;
    if (i < 16384) ws[i] = 0.0f;  // first 64 KB: u, v, err, counters
}

// ---------------- build C[i][j] = sum_d (x_i - y_j)^2 (fp32, exact) --------
__global__ __launch_bounds__(256) void build_dist(const float* __restrict__ A,
                                                  const float* __restrict__ B,
                                                  float* __restrict__ Dst) {
    __shared__ float As[64][68];
    __shared__ float Bs[64][68];
    const int i0 = blockIdx.y << 6, j0 = blockIdx.x << 6;
    const int t = threadIdx.x;
    const float* Ag = A + (size_t)i0 * DIM;
    const float* Bg = B + (size_t)j0 * DIM;
    for (int k = t; k < 4096; k += 256) {
        As[k >> 6][k & 63] = Ag[k];
        Bs[k >> 6][k & 63] = Bg[k];
    }
    __syncthreads();
    const int ty = t >> 4, tx = t & 15;
    float acc[4][4] = {{0.f}};
    for (int d = 0; d < DIM; d += 4) {
        float4 av[4], bv[4];
#pragma unroll
        for (int a = 0; a < 4; ++a) av[a] = *(const float4*)&As[ty + 16 * a][d];
#pragma unroll
        for (int b = 0; b < 4; ++b) bv[b] = *(const float4*)&Bs[tx + 16 * b][d];
#pragma unroll
        for (int a = 0; a < 4; ++a)
#pragma unroll
            for (int b = 0; b < 4; ++b) {
                float d0 = av[a].x - bv[b].x;
                float d1 = av[a].y - bv[b].y;
                float d2 = av[a].z - bv[b].z;
                float d3 = av[a].w - bv[b].w;
                acc[a][b] = fmaf(d0, d0, acc[a][b]);
                acc[a][b] = fmaf(d1, d1, acc[a][b]);
                acc[a][b] = fmaf(d2, d2, acc[a][b]);
                acc[a][b] = fmaf(d3, d3, acc[a][b]);
            }
    }
#pragma unroll
    for (int a = 0; a < 4; ++a) {
        int i = i0 + ty + 16 * a;
        float* drow = Dst + (size_t)i * N + j0;
#pragma unroll
        for (int b = 0; b < 4; ++b) drow[tx + 16 * b] = acc[a][b];
    }
}

// ---------------- quantize C -> u16 panels (step 1/128) --------------------
// grid 4096 (row), block 512. thread t: cols 8t..8t+7 -> panel t>>6.
__global__ __launch_bounds__(512) void quantize_c(const float* __restrict__ C,
                                                  unsigned short* __restrict__ C16) {
    const int i = blockIdx.x, t = threadIdx.x;
    const float4* crow = (const float4*)(C + (size_t)i * N);
    float4 a = crow[2 * t], b = crow[2 * t + 1];
    float vals[8] = {a.x, a.y, a.z, a.w, b.x, b.y, b.z, b.w};
    unsigned short q[8];
#pragma unroll
    for (int e = 0; e < 8; ++e)
        q[e] = (unsigned short)(fminf(vals[e], 511.0f) * QSCALE + 0.5f);
    const int k = t >> 6, cin = (t & 63) * 8;
    size_t off = ((size_t)k << 21) + (size_t)i * 512 + cin;
    *(uint4*)(C16 + off) = *(const uint4*)q;
}

// ---------------- grid-wide sense-reversal barrier (cross-XCD safe) --------
__device__ __forceinline__ void grid_barrier(unsigned* cnt, unsigned* gen) {
    __syncthreads();
    if (threadIdx.x == 0) {
        __threadfence();
        unsigned g = __hip_atomic_load(gen, __ATOMIC_RELAXED, __HIP_MEMORY_SCOPE_AGENT);
        unsigned arrived =
            __hip_atomic_fetch_add(cnt, 1u, __ATOMIC_ACQ_REL, __HIP_MEMORY_SCOPE_AGENT);
        if (arrived == NBLK - 1u) {
            __hip_atomic_store(cnt, 0u, __ATOMIC_RELAXED, __HIP_MEMORY_SCOPE_AGENT);
            __hip_atomic_store(gen, g + 1u, __ATOMIC_RELEASE, __HIP_MEMORY_SCOPE_AGENT);
        } else {
            while (__hip_atomic_load(gen, __ATOMIC_ACQUIRE, __HIP_MEMORY_SCOPE_AGENT) == g)
                __builtin_amdgcn_s_sleep(1);
        }
        __threadfence();
    }
    __syncthreads();
}

__device__ __forceinline__ void lse_merge(float& m, float& s, float mo, float so) {
    float nm = fmaxf(m, mo);
    s = s * __expf(m - nm) + so * __expf(mo - nm);
    m = nm;
}

// ---------------- persistent Sinkhorn: panel-local iterations --------------
__global__ __launch_bounds__(NTHR, 4) void sinkhorn_persist(
    const float* __restrict__ C, const unsigned short* __restrict__ C16,
    float* __restrict__ ws, float* __restrict__ pi, float* __restrict__ out,
    float target) {
    float* u = ws;
    float* v = ws + N;
    float* err = ws + 2 * N;
    float* cost_ws = ws + 2 * N + 64;
    unsigned* done_cnt = (unsigned*)(ws + 2 * N + 65);
    unsigned* bar_cnt = (unsigned*)(ws + 2 * N + 66);
    unsigned* bar_gen = (unsigned*)(ws + 2 * N + 67);
    float2* up = (float2*)((char*)ws + 65536);  // [8][4096]

    const int t = threadIdx.x, wave = t >> 6, lane = t & 63;
    const int xcd = (int)blockIdx.x & 7;        // round-robin block->XCD
    const int b = (int)blockIdx.x >> 3;         // 0..31 within XCD
    const unsigned short* __restrict__ panel = C16 + ((size_t)xcd << 21);

    __shared__ float svec[N];        // staged u (phase C) / v (final)
    __shared__ float2 wred[16][16];  // phase C cross-wave partials
    __shared__ float red[16];
    __shared__ float bcast;

    for (int it = 0; it < MAX_ITER; ++it) {
        // ======== phase A: row-partial LSE over this XCD's 512 columns ====
        {
            const float* vg = v + (xcd << 9) + lane * 8;
            float4 vv0 = *(const float4*)vg;
            float4 vv1 = *(const float4*)(vg + 4);
            const int rbase = b * 128 + wave * 8;
            uint4 craw[8];
#pragma unroll
            for (int r = 0; r < 8; ++r)
                craw[r] = *(const uint4*)(panel + (size_t)(rbase + r) * 512 + lane * 8);
#pragma unroll
            for (int r = 0; r < 8; ++r) {
                uint4 cw = craw[r];
                float z0 = (vv0.x - (float)(cw.x & 0xffffu) * IQSCALE) * INV_EPS;
                float z1 = (vv0.y - (float)(cw.x >> 16) * IQSCALE) * INV_EPS;
                float z2 = (vv0.z - (float)(cw.y & 0xffffu) * IQSCALE) * INV_EPS;
                float z3 = (vv0.w - (float)(cw.y >> 16) * IQSCALE) * INV_EPS;
                float z4 = (vv1.x - (float)(cw.z & 0xffffu) * IQSCALE) * INV_EPS;
                float z5 = (vv1.y - (float)(cw.z >> 16) * IQSCALE) * INV_EPS;
                float z6 = (vv1.z - (float)(cw.w & 0xffffu) * IQSCALE) * INV_EPS;
                float z7 = (vv1.w - (float)(cw.w >> 16) * IQSCALE) * INV_EPS;
                float m = fmaxf(fmaxf(fmaxf(z0, z1), fmaxf(z2, z3)),
                                fmaxf(fmaxf(z4, z5), fmaxf(z6, z7)));
#pragma unroll
                for (int off = 32; off; off >>= 1) m = fmaxf(m, __shfl_xor(m, off));
                float s = __expf(z0 - m) + __expf(z1 - m) + __expf(z2 - m) +
                          __expf(z3 - m) + __expf(z4 - m) + __expf(z5 - m) +
                          __expf(z6 - m) + __expf(z7 - m);
#pragma unroll
                for (int off = 32; off; off >>= 1) s += __shfl_xor(s, off);
                if (lane == 0)
                    up[((size_t)xcd << 12) + rbase + r] = make_float2(m, s);
            }
        }
        grid_barrier(bar_cnt, bar_gen);

        // ======== phase B: merge 8 panel-partials -> u_new + err ==========
        if (t < 16) {
            const int row = ((int)blockIdx.x << 4) + t;
            float m = -1e30f, s = 0.0f;
#pragma unroll
            for (int k = 0; k < 8; ++k) {
                float2 p = up[((size_t)k << 12) + row];
                lse_merge(m, s, p.x, p.y);
            }
            float un = target - EPS * (m + __logf(s));
            float uo = u[row];
            u[row] = un;
            red[t] = fabsf(un - uo);
        }
        __syncthreads();
        if (t == 0) {
            float e = 0.f;
#pragma unroll
            for (int k = 0; k < 16; ++k) e += red[k];
            atomicAdd(&err[it], e);
        }
        grid_barrier(bar_cnt, bar_gen);

        // ======== phase C: column LSE for this block's 16 columns =========
        ((float4*)svec)[t] = ((const float4*)u)[t];
        __syncthreads();
        {
            const int c = lane & 15, rloc = lane >> 4;
            const int colin = b * 16 + c;
            const int rstart = wave * 256 + rloc;
            float m0 = -1e30f, m1 = -1e30f, s0 = 0.f, s1 = 0.f;
#pragma unroll 4
            for (int step = 0; step < 64; ++step) {
                int row = rstart + step * 4;
                float cv = (float)panel[(size_t)row * 512 + colin] * IQSCALE;
                float z = (svec[row] - cv) * INV_EPS;
                if (step & 1) {
                    float nm = fmaxf(m1, z);
                    s1 = s1 * __expf(m1 - nm) + __expf(z - nm);
                    m1 = nm;
                } else {
                    float nm = fmaxf(m0, z);
                    s0 = s0 * __expf(m0 - nm) + __expf(z - nm);
                    m0 = nm;
                }
            }
            lse_merge(m0, s0, m1, s1);
            // merge across the 4 lanes sharing a column (rloc dim)
#pragma unroll
            for (int off = 16; off <= 32; off <<= 1) {
                float mo = __shfl_xor(m0, off);
                float so = __shfl_xor(s0, off);
                lse_merge(m0, s0, mo, so);
            }
            if (rloc == 0) wred[wave][c] = make_float2(m0, s0);
        }
        __syncthreads();
        if (t < 16) {
            float m = -1e30f, s = 0.0f;
#pragma unroll
            for (int w = 0; w < 16; ++w) {
                float2 p = wred[w][t];
                lse_merge(m, s, p.x, p.y);
            }
            v[(xcd << 9) + b * 16 + t] = target - EPS * (m + __logf(s));
        }
        grid_barrier(bar_cnt, bar_gen);

        // ======== convergence (reference's freeze semantics) ==============
        if (t == 0)
            bcast = __hip_atomic_load(&err[it], __ATOMIC_RELAXED, __HIP_MEMORY_SCOPE_AGENT);
        __syncthreads();
        if (bcast < THRESH) break;
    }

    // ======== final: pi = exp((u_i + v_j - C)/eps), cost = sum(pi*C) ======
    ((float4*)svec)[t] = ((const float4*)v)[t];
    __syncthreads();
    const int row = ((int)blockIdx.x << 4) + wave;
    const float4* __restrict__ Crow = (const float4*)(C + (size_t)row * N);
    float4* __restrict__ pirow = (float4*)(pi + (size_t)row * N);
    const float ui = u[row];
    float csum = 0.f;
#pragma unroll 4
    for (int cb = 0; cb < 16; ++cb) {
        int idx = cb * 64 + lane;
        float4 c = Crow[idx];
        float4 w = ((const float4*)svec)[idx];
        float4 p;
        p.x = __expf((ui + w.x - c.x) * INV_EPS);
        p.y = __expf((ui + w.y - c.y) * INV_EPS);
        p.z = __expf((ui + w.z - c.z) * INV_EPS);
        p.w = __expf((ui + w.w - c.w) * INV_EPS);
        pirow[idx] = p;
        csum = fmaf(p.x, c.x, csum);
        csum = fmaf(p.y, c.y, csum);
        csum = fmaf(p.z, c.z, csum);
        csum = fmaf(p.w, c.w, csum);
    }
#pragma unroll
    for (int off = 32; off; off >>= 1) csum += __shfl_xor(csum, off);
    if (lane == 0) red[wave] = csum;
    __syncthreads();
    if (t == 0) {
        float cs = 0.f;
#pragma unroll
        for (int k = 0; k < 16; ++k) cs += red[k];
        atomicAdd(cost_ws, cs);
        __threadfence();
        unsigned a =
            __hip_atomic_fetch_add(done_cnt, 1u, __ATOMIC_ACQ_REL, __HIP_MEMORY_SCOPE_AGENT);
        if (a == NBLK - 1u)
            out[0] = __hip_atomic_load(cost_ws, __ATOMIC_RELAXED, __HIP_MEMORY_SCOPE_AGENT);
    }
}

extern "C" void kernel_launch(void* const* d_in, const int* in_sizes, int n_in,
                              void* d_out, int out_size, void* d_ws, size_t ws_size,
                              hipStream_t stream) {
    const float* x = (const float*)d_in[0];  // [4096,64]
    const float* y = (const float*)d_in[1];  // [4096,64]
    float* out = (float*)d_out;              // [0]=cost, [1..N*N]=pi, [1+N*N..]=C
    float* pi = out + 1;
    float* C = out + 1 + (size_t)N * N;
    float* ws = (float*)d_ws;
    unsigned short* C16 = (unsigned short*)((char*)d_ws + (1 << 20));

    init_ws<<<dim3(64), dim3(256), 0, stream>>>(ws);

    build_dist<<<dim3(64, 64), dim3(256), 0, stream>>>(x, y, C);
    quantize_c<<<dim3(N), dim3(512), 0, stream>>>(C, C16);

    float target = EPS * logf(1.0f / (float)N + 1e-8f);  // log_mu == log_nu

    sinkhorn_persist<<<dim3(NBLK), dim3(NTHR), 0, stream>>>(C, C16, ws, pi, out, target);
}

// Round 6
// 5388.313 us; speedup vs baseline: 1.2709x; 1.2709x over previous
//
#include <hip/hip_runtime.h>
#include <math.h>

#define N 4096
#define DIM 64
#define MAX_ITER 50
#define EPS 0.1f
#define INV_EPS 10.0f
#define THRESH 0.1f
#define NBLK 256
#define NTHR 1024
#define QSCALE 128.0f
#define IQSCALE 0.0078125f

// ws layout (bytes):
//   [0,16K) u | [16K,32K) v | [32K,+) err[64] floats
//   [64K,320K) up: float2 up[8][4096] row-partials
//   [320K,352K) flags: 256 x 128B-spaced uint (tree-barrier arrival)
//   [352K,353K) rel: 8 x 128B-spaced uint (release replicas)
//   [356K,388K) errpart: 256 x 128B-spaced float
//   [388K,420K) costpart: 256 x 128B-spaced float
//   [1M,33M) C16 panels: panel k at 1M+k*4MiB, row-major 4096x512 u16
#define UP_OFF 65536
#define FLAGS_OFF (320 * 1024)
#define REL_OFF (352 * 1024)
#define ERRP_OFF (356 * 1024)
#define COSTP_OFF (388 * 1024)
#define C16_OFF (1 << 20)

__global__ void init_ws(float* __restrict__ ws) {
    int i = blockIdx.x * 256 + threadIdx.x;
    if (i < COSTP_OFF / 4 + 8192) ws[i] = 0.0f;  // zero everything below C16
}

// ---------------- build C[i][j] = sum_d (x_i - y_j)^2 (fp32, exact) --------
__global__ __launch_bounds__(256) void build_dist(const float* __restrict__ A,
                                                  const float* __restrict__ B,
                                                  float* __restrict__ Dst) {
    __shared__ float As[64][68];
    __shared__ float Bs[64][68];
    const int i0 = blockIdx.y << 6, j0 = blockIdx.x << 6;
    const int t = threadIdx.x;
    const float* Ag = A + (size_t)i0 * DIM;
    const float* Bg = B + (size_t)j0 * DIM;
    for (int k = t; k < 4096; k += 256) {
        As[k >> 6][k & 63] = Ag[k];
        Bs[k >> 6][k & 63] = Bg[k];
    }
    __syncthreads();
    const int ty = t >> 4, tx = t & 15;
    float acc[4][4] = {{0.f}};
    for (int d = 0; d < DIM; d += 4) {
        float4 av[4], bv[4];
#pragma unroll
        for (int a = 0; a < 4; ++a) av[a] = *(const float4*)&As[ty + 16 * a][d];
#pragma unroll
        for (int b = 0; b < 4; ++b) bv[b] = *(const float4*)&Bs[tx + 16 * b][d];
#pragma unroll
        for (int a = 0; a < 4; ++a)
#pragma unroll
            for (int b = 0; b < 4; ++b) {
                float d0 = av[a].x - bv[b].x;
                float d1 = av[a].y - bv[b].y;
                float d2 = av[a].z - bv[b].z;
                float d3 = av[a].w - bv[b].w;
                acc[a][b] = fmaf(d0, d0, acc[a][b]);
                acc[a][b] = fmaf(d1, d1, acc[a][b]);
                acc[a][b] = fmaf(d2, d2, acc[a][b]);
                acc[a][b] = fmaf(d3, d3, acc[a][b]);
            }
    }
#pragma unroll
    for (int a = 0; a < 4; ++a) {
        int i = i0 + ty + 16 * a;
        float* drow = Dst + (size_t)i * N + j0;
#pragma unroll
        for (int b = 0; b < 4; ++b) drow[tx + 16 * b] = acc[a][b];
    }
}

// ---------------- quantize C -> u16 panels (step 1/128) --------------------
__global__ __launch_bounds__(512) void quantize_c(const float* __restrict__ C,
                                                  unsigned short* __restrict__ C16) {
    const int i = blockIdx.x, t = threadIdx.x;
    const float4* crow = (const float4*)(C + (size_t)i * N);
    float4 a = crow[2 * t], b = crow[2 * t + 1];
    float vals[8] = {a.x, a.y, a.z, a.w, b.x, b.y, b.z, b.w};
    unsigned short q[8];
#pragma unroll
    for (int e = 0; e < 8; ++e)
        q[e] = (unsigned short)(fminf(vals[e], 511.0f) * QSCALE + 0.5f);
    const int k = t >> 6, cin = (t & 63) * 8;
    size_t off = ((size_t)k << 21) + (size_t)i * 512 + cin;
    *(uint4*)(C16 + off) = *(const uint4*)q;
}

// ---------------- contention-free tree barrier -----------------------------
// Arrival: each block release-stores `epoch` to its own 128B-spaced flag
// (no RMW, no shared line). Block 0: 256 threads poll the 256 flags in
// parallel, then publish epoch to 8 replicated release lines. Other blocks
// poll replica (blockIdx&7): ~32 pollers/line.
__device__ __forceinline__ void tree_barrier(unsigned* flags, unsigned* rel,
                                             unsigned epoch) {
    const int t = threadIdx.x;
    __syncthreads();
    if (blockIdx.x == 0) {
        if (t > 0 && t < NBLK) {
            while (__hip_atomic_load(&flags[t * 32], __ATOMIC_ACQUIRE,
                                     __HIP_MEMORY_SCOPE_AGENT) != epoch)
                __builtin_amdgcn_s_sleep(1);
        }
        __syncthreads();
        if (t < 8)
            __hip_atomic_store(&rel[t * 32], epoch, __ATOMIC_RELEASE,
                               __HIP_MEMORY_SCOPE_AGENT);
        __syncthreads();
    } else {
        if (t == 0) {
            __hip_atomic_store(&flags[(int)blockIdx.x * 32], epoch,
                               __ATOMIC_RELEASE, __HIP_MEMORY_SCOPE_AGENT);
            const int g = (int)blockIdx.x & 7;
            while (__hip_atomic_load(&rel[g * 32], __ATOMIC_ACQUIRE,
                                     __HIP_MEMORY_SCOPE_AGENT) != epoch)
                __builtin_amdgcn_s_sleep(1);
        }
        __syncthreads();
    }
}

__device__ __forceinline__ void lse_merge(float& m, float& s, float mo, float so) {
    float nm = fmaxf(m, mo);
    s = s * __expf(m - nm) + so * __expf(mo - nm);
    m = nm;
}

// ---------------- persistent Sinkhorn: panel-local iterations --------------
__global__ __launch_bounds__(NTHR, 4) void sinkhorn_persist(
    const float* __restrict__ C, const unsigned short* __restrict__ C16,
    float* __restrict__ ws, float* __restrict__ pi, float* __restrict__ out,
    float target) {
    float* u = ws;
    float* v = ws + N;
    float* err = ws + 2 * N;
    float2* up = (float2*)((char*)ws + UP_OFF);
    unsigned* flags = (unsigned*)((char*)ws + FLAGS_OFF);
    unsigned* rel = (unsigned*)((char*)ws + REL_OFF);
    float* errpart = (float*)((char*)ws + ERRP_OFF);
    float* costpart = (float*)((char*)ws + COSTP_OFF);

    const int t = threadIdx.x, wave = t >> 6, lane = t & 63;
    const int xcd = (int)blockIdx.x & 7;  // round-robin block->XCD heuristic
    const int b = (int)blockIdx.x >> 3;   // 0..31 within XCD
    const unsigned short* __restrict__ panel = C16 + ((size_t)xcd << 21);

    __shared__ float svec[N];        // staged u (phase C) / v (final)
    __shared__ float2 wred[16][16];  // phase C cross-wave partials
    __shared__ float red[16];
    __shared__ float bcast;

    unsigned epoch = 0;

    for (int it = 0; it < MAX_ITER; ++it) {
        // ======== phase A: row-partial LSE over this XCD's 512 columns ====
        {
            const float* vg = v + (xcd << 9) + lane * 8;
            float4 vv0 = *(const float4*)vg;
            float4 vv1 = *(const float4*)(vg + 4);
            const int rbase = b * 128 + wave * 8;
            uint4 craw[8];
#pragma unroll
            for (int r = 0; r < 8; ++r)
                craw[r] = *(const uint4*)(panel + (size_t)(rbase + r) * 512 + lane * 8);
#pragma unroll
            for (int r = 0; r < 8; ++r) {
                uint4 cw = craw[r];
                float z0 = (vv0.x - (float)(cw.x & 0xffffu) * IQSCALE) * INV_EPS;
                float z1 = (vv0.y - (float)(cw.x >> 16) * IQSCALE) * INV_EPS;
                float z2 = (vv0.z - (float)(cw.y & 0xffffu) * IQSCALE) * INV_EPS;
                float z3 = (vv0.w - (float)(cw.y >> 16) * IQSCALE) * INV_EPS;
                float z4 = (vv1.x - (float)(cw.z & 0xffffu) * IQSCALE) * INV_EPS;
                float z5 = (vv1.y - (float)(cw.z >> 16) * IQSCALE) * INV_EPS;
                float z6 = (vv1.z - (float)(cw.w & 0xffffu) * IQSCALE) * INV_EPS;
                float z7 = (vv1.w - (float)(cw.w >> 16) * IQSCALE) * INV_EPS;
                float m = fmaxf(fmaxf(fmaxf(z0, z1), fmaxf(z2, z3)),
                                fmaxf(fmaxf(z4, z5), fmaxf(z6, z7)));
#pragma unroll
                for (int off = 32; off; off >>= 1) m = fmaxf(m, __shfl_xor(m, off));
                float s = __expf(z0 - m) + __expf(z1 - m) + __expf(z2 - m) +
                          __expf(z3 - m) + __expf(z4 - m) + __expf(z5 - m) +
                          __expf(z6 - m) + __expf(z7 - m);
#pragma unroll
                for (int off = 32; off; off >>= 1) s += __shfl_xor(s, off);
                if (lane == 0)
                    up[((size_t)xcd << 12) + rbase + r] = make_float2(m, s);
            }
        }
        tree_barrier(flags, rel, ++epoch);

        // ======== phase B: merge 8 panel-partials -> u_new + err part =====
        if (t < 16) {
            const int row = ((int)blockIdx.x << 4) + t;
            float m = -1e30f, s = 0.0f;
#pragma unroll
            for (int k = 0; k < 8; ++k) {
                float2 p = up[((size_t)k << 12) + row];
                lse_merge(m, s, p.x, p.y);
            }
            float un = target - EPS * (m + __logf(s));
            float uo = u[row];
            u[row] = un;
            red[t] = fabsf(un - uo);
        }
        __syncthreads();
        if (t == 0) {
            float e = 0.f;
#pragma unroll
            for (int k = 0; k < 16; ++k) e += red[k];
            errpart[(int)blockIdx.x * 32] = e;  // own 128B slot, no atomic
        }
        tree_barrier(flags, rel, ++epoch);

        // ======== phase C: column LSE for this block's 16 columns =========
        ((float4*)svec)[t] = ((const float4*)u)[t];
        __syncthreads();
        {
            const int c = lane & 15, rloc = lane >> 4;
            const int colin = b * 16 + c;
            const int rstart = wave * 256 + rloc;
            float m0 = -1e30f, m1 = -1e30f, s0 = 0.f, s1 = 0.f;
#pragma unroll 8
            for (int step = 0; step < 64; ++step) {
                int row = rstart + step * 4;
                float cv = (float)panel[(size_t)row * 512 + colin] * IQSCALE;
                float z = (svec[row] - cv) * INV_EPS;
                if (step & 1) {
                    float nm = fmaxf(m1, z);
                    s1 = s1 * __expf(m1 - nm) + __expf(z - nm);
                    m1 = nm;
                } else {
                    float nm = fmaxf(m0, z);
                    s0 = s0 * __expf(m0 - nm) + __expf(z - nm);
                    m0 = nm;
                }
            }
            lse_merge(m0, s0, m1, s1);
#pragma unroll
            for (int off = 16; off <= 32; off <<= 1) {
                float mo = __shfl_xor(m0, off);
                float so = __shfl_xor(s0, off);
                lse_merge(m0, s0, mo, so);
            }
            if (rloc == 0) wred[wave][c] = make_float2(m0, s0);
        }
        __syncthreads();
        if (t < 16) {
            float m = -1e30f, s = 0.0f;
#pragma unroll
            for (int w = 0; w < 16; ++w) {
                float2 p = wred[w][t];
                lse_merge(m, s, p.x, p.y);
            }
            v[(xcd << 9) + b * 16 + t] = target - EPS * (m + __logf(s));
        }
        __syncthreads();
        // block 0 additionally reduces the 256 err partials -> err[it],
        // published to everyone via barrier 3's release chain.
        if (blockIdx.x == 0) {
            float e = (t < NBLK) ? errpart[t * 32] : 0.0f;
#pragma unroll
            for (int off = 32; off; off >>= 1) e += __shfl_xor(e, off);
            if (lane == 0) red[wave] = e;
            __syncthreads();
            if (t == 0) {
                float tot = 0.f;
#pragma unroll
                for (int k = 0; k < 16; ++k) tot += red[k];
                err[it] = tot;
            }
        }
        tree_barrier(flags, rel, ++epoch);

        // ======== convergence (reference's freeze semantics) ==============
        if (t == 0) bcast = err[it];
        __syncthreads();
        if (bcast < THRESH) break;
    }

    // ======== final: pi = exp((u_i + v_j - C)/eps), cost = sum(pi*C) ======
    ((float4*)svec)[t] = ((const float4*)v)[t];
    __syncthreads();
    const int row = ((int)blockIdx.x << 4) + wave;
    const float4* __restrict__ Crow = (const float4*)(C + (size_t)row * N);
    float4* __restrict__ pirow = (float4*)(pi + (size_t)row * N);
    const float ui = u[row];
    float csum = 0.f;
#pragma unroll 4
    for (int cb = 0; cb < 16; ++cb) {
        int idx = cb * 64 + lane;
        float4 c = Crow[idx];
        float4 w = ((const float4*)svec)[idx];
        float4 p;
        p.x = __expf((ui + w.x - c.x) * INV_EPS);
        p.y = __expf((ui + w.y - c.y) * INV_EPS);
        p.z = __expf((ui + w.z - c.z) * INV_EPS);
        p.w = __expf((ui + w.w - c.w) * INV_EPS);
        pirow[idx] = p;
        csum = fmaf(p.x, c.x, csum);
        csum = fmaf(p.y, c.y, csum);
        csum = fmaf(p.z, c.z, csum);
        csum = fmaf(p.w, c.w, csum);
    }
#pragma unroll
    for (int off = 32; off; off >>= 1) csum += __shfl_xor(csum, off);
    if (lane == 0) red[wave] = csum;
    __syncthreads();
    if (t == 0) {
        float cs = 0.f;
#pragma unroll
        for (int k = 0; k < 16; ++k) cs += red[k];
        costpart[(int)blockIdx.x * 32] = cs;  // own slot, no atomic
    }
    // arrive-only final sync; block 0 gathers and writes the cost scalar
    ++epoch;
    __syncthreads();
    if (blockIdx.x == 0) {
        if (t > 0 && t < NBLK) {
            while (__hip_atomic_load(&flags[t * 32], __ATOMIC_ACQUIRE,
                                     __HIP_MEMORY_SCOPE_AGENT) != epoch)
                __builtin_amdgcn_s_sleep(1);
        }
        __syncthreads();
        float cp = (t < NBLK) ? costpart[t * 32] : 0.0f;
#pragma unroll
        for (int off = 32; off; off >>= 1) cp += __shfl_xor(cp, off);
        if (lane == 0) red[wave] = cp;
        __syncthreads();
        if (t == 0) {
            float tot = 0.f;
#pragma unroll
            for (int k = 0; k < 16; ++k) tot += red[k];
            out[0] = tot;
        }
    } else {
        if (t == 0)
            __hip_atomic_store(&flags[(int)blockIdx.x * 32], epoch,
                               __ATOMIC_RELEASE, __HIP_MEMORY_SCOPE_AGENT);
    }
}

extern "C" void kernel_launch(void* const* d_in, const int* in_sizes, int n_in,
                              void* d_out, int out_size, void* d_ws, size_t ws_size,
                              hipStream_t stream) {
    const float* x = (const float*)d_in[0];  // [4096,64]
    const float* y = (const float*)d_in[1];  // [4096,64]
    float* out = (float*)d_out;              // [0]=cost, [1..N*N]=pi, [1+N*N..]=C
    float* pi = out + 1;
    float* C = out + 1 + (size_t)N * N;
    float* ws = (float*)d_ws;
    unsigned short* C16 = (unsigned short*)((char*)d_ws + C16_OFF);

    init_ws<<<dim3(512), dim3(256), 0, stream>>>(ws);

    build_dist<<<dim3(64, 64), dim3(256), 0, stream>>>(x, y, C);
    quantize_c<<<dim3(N), dim3(512), 0, stream>>>(C, C16);

    float target = EPS * logf(1.0f / (float)N + 1e-8f);  // log_mu == log_nu

    sinkhorn_persist<<<dim3(NBLK), dim3(NTHR), 0, stream>>>(C, C16, ws, pi, out, target);
}